// Round 5
// baseline (71.733 us; speedup 1.0000x reference)
//
#include <hip/hip_runtime.h>

// out[b,u] = prod_i ( x[b,i]*w[i,u] + (1 - w[i,u]) ) = prod_i ( 1 + w[i,u]*(x[b,i]-1) )
// B=2048, IN_DIM=256, UNITS=512
//
// Round 11: FORCED scalar w loads. R10 (same mapping, compiler-chosen loads)
// was neutral vs R8 => w loads likely stayed per-lane VMEM (512
// global_load_dwordx2/wave on the shared L1 port ~= the old LDS-port cost).
// Now w rows are fetched via inline-asm s_load_dwordx16 (4/ii, 64 SGPRs),
// s_waitcnt carries the tuples as "+s" in/outs so dataflow orders the pk_fma
// after the wait (rule #18). Main loop: 64 pk-VALU/ii + 4 SMEM/ii; zero LDS,
// zero barriers, zero VMEM. Mapping/combine/epilogue identical to R10:
// wave=64 b-lanes, 16 waves=16 i-slices, 4-round XOR-swizzled combine tree.
// Grid (8,32)=256 blocks, 1 block/CU, 4 waves/SIMD.

typedef float v2f  __attribute__((ext_vector_type(2)));
typedef float v16f __attribute__((ext_vector_type(16)));

#define B_DIM   2048
#define IN_DIM  256
#define UNITS   512
#define BT      64      // b per block (= lanes per wave)
#define UT      64      // u per block (all waves same u-tile)
#define BLOCK   1024
#define NW      16      // waves per block = i-slices
#define KIS     16      // i per wave
#define PLANE_F (64*64) // floats per combine plane (16 KB)

__global__ __launch_bounds__(BLOCK, 4) void prodw_kernel(
    const float* __restrict__ x,   // [B, IN_DIM]
    const float* __restrict__ w,   // [IN_DIM, UNITS]
    float* __restrict__ out)       // [B, UNITS]
{
    __shared__ __align__(16) float lds[(NW / 2) * PLANE_F];   // 128 KB

    const int tid  = threadIdx.x;
    const int ln   = tid & 63;                                   // lane = b
    const int wid  = __builtin_amdgcn_readfirstlane(tid >> 6);   // wave = i-slice
    const int ublk = blockIdx.x * UT;
    const int bblk = blockIdx.y * BT;

    // ---- y = x-1 for this lane's b-row, this wave's i-slice (registers) ----
    float yv[KIS];
    {
        const float* xp = x + (size_t)(bblk + ln) * IN_DIM + wid * KIS;
#pragma unroll
        for (int k = 0; k < KIS / 4; ++k) {
            const float4 f = *(const float4*)(xp + 4 * k);
            yv[4 * k + 0] = f.x - 1.0f;
            yv[4 * k + 1] = f.y - 1.0f;
            yv[4 * k + 2] = f.z - 1.0f;
            yv[4 * k + 3] = f.w - 1.0f;
        }
    }

    v2f acc[32];
#pragma unroll
    for (int q = 0; q < 32; ++q) acc[q] = (v2f){1.0f, 1.0f};

    // wave-uniform w row base (derived from readfirstlane/blockIdx only)
    const float* wp = w + (size_t)(wid * KIS) * UNITS + ublk;

    // ---- main loop: SMEM w + pk VALU only; no LDS, no barriers, no VMEM ----
#pragma unroll 1
    for (int ii = 0; ii < KIS; ++ii) {
        const float* wr = wp + (size_t)ii * UNITS;   // uniform
        v16f w0, w1, w2, w3;
        asm volatile("s_load_dwordx16 %0, %1, 0x0"  : "=s"(w0) : "s"(wr));
        asm volatile("s_load_dwordx16 %0, %1, 0x40" : "=s"(w1) : "s"(wr));
        asm volatile("s_load_dwordx16 %0, %1, 0x80" : "=s"(w2) : "s"(wr));
        asm volatile("s_load_dwordx16 %0, %1, 0xc0" : "=s"(w3) : "s"(wr));
        // dataflow fence: consumers read the post-wait tuples (rule #18)
        asm volatile("s_waitcnt lgkmcnt(0)"
                     : "+s"(w0), "+s"(w1), "+s"(w2), "+s"(w3));

        const v2f yy = {yv[ii], yv[ii]};
#pragma unroll
        for (int j = 0; j < 8; ++j) {
            const v2f wv = {w0[2 * j], w0[2 * j + 1]};
            acc[j] *= __builtin_elementwise_fma(wv, yy, (v2f){1.0f, 1.0f});
        }
#pragma unroll
        for (int j = 0; j < 8; ++j) {
            const v2f wv = {w1[2 * j], w1[2 * j + 1]};
            acc[8 + j] *= __builtin_elementwise_fma(wv, yy, (v2f){1.0f, 1.0f});
        }
#pragma unroll
        for (int j = 0; j < 8; ++j) {
            const v2f wv = {w2[2 * j], w2[2 * j + 1]};
            acc[16 + j] *= __builtin_elementwise_fma(wv, yy, (v2f){1.0f, 1.0f});
        }
#pragma unroll
        for (int j = 0; j < 8; ++j) {
            const v2f wv = {w3[2 * j], w3[2 * j + 1]};
            acc[24 + j] *= __builtin_elementwise_fma(wv, yy, (v2f){1.0f, 1.0f});
        }
    }

    // ---- combine across 16 waves (elementwise product), XOR-swizzled b128 ----
#pragma unroll
    for (int half = NW / 2; half >= 1; half >>= 1) {
        __syncthreads();
        if (wid >= half && wid < 2 * half) {
            float* pl = lds + (size_t)(wid - half) * PLANE_F + ln * 64;
#pragma unroll
            for (int k = 0; k < 16; ++k)
                *(float4*)&pl[(4 * k) ^ ((ln & 7) << 2)] = ((const float4*)acc)[k];
        }
        __syncthreads();
        if (wid < half) {
            const float* pl = lds + (size_t)wid * PLANE_F + ln * 64;
#pragma unroll
            for (int k = 0; k < 16; ++k) {
                const float4 qv = *(const float4*)&pl[(4 * k) ^ ((ln & 7) << 2)];
                float4* a4 = &((float4*)acc)[k];
                a4->x *= qv.x; a4->y *= qv.y; a4->z *= qv.z; a4->w *= qv.w;
            }
        }
    }

    // ---- wave 0 stores its lane's b-row u-span (256B contiguous per lane) ----
    if (wid == 0) {
        float* po = out + (size_t)(bblk + ln) * UNITS + ublk;
#pragma unroll
        for (int k = 0; k < 16; ++k)
            *(float4*)(po + 4 * k) = ((const float4*)acc)[k];
    }
}

extern "C" void kernel_launch(void* const* d_in, const int* in_sizes, int n_in,
                              void* d_out, int out_size, void* d_ws, size_t ws_size,
                              hipStream_t stream) {
    const float* x = (const float*)d_in[0];        // 2048*256
    const float* w = (const float*)d_in[1];        // 256*512
    float* out     = (float*)d_out;                // 2048*512

    dim3 grid(UNITS / UT, B_DIM / BT);             // (8, 32) = 256 blocks
    prodw_kernel<<<grid, BLOCK, 0, stream>>>(x, w, out);
}

// Round 7
// 71.310 us; speedup vs baseline: 1.0059x; 1.0059x over previous
//
#include <hip/hip_runtime.h>

// out[b,u] = prod_i ( x[b,i]*w[i,u] + (1 - w[i,u]) ) = prod_i ( 1 + w[i,u]*(x[b,i]-1) )
// B=2048, IN_DIM=256, UNITS=512
//
// Round 13: occupancy test, correctness-safe. R12 FAILED: split issue/wait
// SMEM inline-asm is unsound (compiler may copy/spill the in-flight "=s"
// destination between issue and wait -> stale data). Reverted to R10's plain
// uniform-pointer w loads (compiler-chosen; proven absmax 3.76e-37).
// The actual experiment (8 waves/SIMD) is kept: per-thread tile halved
// (UT=32, acc 32 VGPR, y in 8-reg chunks), __launch_bounds__(1024,8),
// LDS 64 KB -> 2 blocks/CU, grid (16,32)=512 blocks, 32 waves/CU.
// Main loop: zero LDS, zero barriers; w latency hidden by TLP (8 waves/SIMD).
// Combine: 4-round XOR-swizzled b128 tree; wave 0 stores.
// Decode: dur 64-67 => stalls were occupancy-curable; dur ~70-72 => VALU
// issue already saturated at 4 waves (floor 2 ops/term, 6.8us main loop).

typedef float v2f __attribute__((ext_vector_type(2)));

#define B_DIM   2048
#define IN_DIM  256
#define UNITS   512
#define BT      64      // b per block (= lanes per wave)
#define UT      32      // u per block (all 16 waves same u-tile)
#define BLOCK   1024
#define NW      16      // waves per block = i-slices
#define KIS     16      // i per wave
#define PLANE_F (64*32) // floats per combine plane (8 KB)

__global__ __launch_bounds__(BLOCK, 8) void prodw_kernel(
    const float* __restrict__ x,   // [B, IN_DIM]
    const float* __restrict__ w,   // [IN_DIM, UNITS]
    float* __restrict__ out)       // [B, UNITS]
{
    __shared__ __align__(16) float lds[(NW / 2) * PLANE_F];   // 64 KB

    const int tid  = threadIdx.x;
    const int ln   = tid & 63;                                   // lane = b
    const int wid  = __builtin_amdgcn_readfirstlane(tid >> 6);   // wave = i-slice
    const int ublk = blockIdx.x * UT;
    const int bblk = blockIdx.y * BT;

    const float* xp = x + (size_t)(bblk + ln) * IN_DIM + wid * KIS;

    // ---- y chunk 0 (i = 0..7 of this slice), registers only ----
    float yv[8];
    {
        const float4 f0 = *(const float4*)(xp + 0);
        const float4 f1 = *(const float4*)(xp + 4);
        yv[0] = f0.x - 1.0f; yv[1] = f0.y - 1.0f;
        yv[2] = f0.z - 1.0f; yv[3] = f0.w - 1.0f;
        yv[4] = f1.x - 1.0f; yv[5] = f1.y - 1.0f;
        yv[6] = f1.z - 1.0f; yv[7] = f1.w - 1.0f;
    }

    v2f acc[16];
#pragma unroll
    for (int q = 0; q < 16; ++q) acc[q] = (v2f){1.0f, 1.0f};

    // wave-uniform w base (all indices from readfirstlane/blockIdx)
    const float* wp = w + (size_t)(wid * KIS) * UNITS + ublk;

    // ---- main loop: zero LDS, zero barriers; compiler-chosen w loads ----
#pragma unroll 2
    for (int r = 0; r < KIS; ++r) {
        // reload y chunk 1 (i = 8..15) just before first use
        if (r == 8) {
            const float4 f0 = *(const float4*)(xp + 8);
            const float4 f1 = *(const float4*)(xp + 12);
            yv[0] = f0.x - 1.0f; yv[1] = f0.y - 1.0f;
            yv[2] = f0.z - 1.0f; yv[3] = f0.w - 1.0f;
            yv[4] = f1.x - 1.0f; yv[5] = f1.y - 1.0f;
            yv[6] = f1.z - 1.0f; yv[7] = f1.w - 1.0f;
        }

        const float* wr = wp + (size_t)r * UNITS;   // wave-uniform row
        const v2f yy = {yv[r & 7], yv[r & 7]};
#pragma unroll
        for (int q = 0; q < 16; ++q) {
            const v2f wv = *(const v2f*)(wr + 2 * q);
            acc[q] *= __builtin_elementwise_fma(wv, yy, (v2f){1.0f, 1.0f});
        }
    }

    // ---- combine across 16 waves (elementwise product), XOR-swizzled b128 ----
#pragma unroll
    for (int half = NW / 2; half >= 1; half >>= 1) {
        __syncthreads();
        if (wid >= half && wid < 2 * half) {
            float* pl = lds + (size_t)(wid - half) * PLANE_F + ln * 32;
#pragma unroll
            for (int k = 0; k < 8; ++k)
                *(float4*)&pl[(4 * k) ^ ((ln & 7) << 2)] = ((const float4*)acc)[k];
        }
        __syncthreads();
        if (wid < half) {
            const float* pl = lds + (size_t)wid * PLANE_F + ln * 32;
#pragma unroll
            for (int k = 0; k < 8; ++k) {
                const float4 qv = *(const float4*)&pl[(4 * k) ^ ((ln & 7) << 2)];
                float4* a4 = &((float4*)acc)[k];
                a4->x *= qv.x; a4->y *= qv.y; a4->z *= qv.z; a4->w *= qv.w;
            }
        }
    }

    // ---- wave 0 stores its lane's b-row u-span (128B contiguous per lane) ----
    if (wid == 0) {
        float* po = out + (size_t)(bblk + ln) * UNITS + ublk;
#pragma unroll
        for (int k = 0; k < 8; ++k)
            *(float4*)(po + 4 * k) = ((const float4*)acc)[k];
    }
}

extern "C" void kernel_launch(void* const* d_in, const int* in_sizes, int n_in,
                              void* d_out, int out_size, void* d_ws, size_t ws_size,
                              hipStream_t stream) {
    const float* x = (const float*)d_in[0];        // 2048*256
    const float* w = (const float*)d_in[1];        // 256*512
    float* out     = (float*)d_out;                // 2048*512

    dim3 grid(UNITS / UT, B_DIM / BT);             // (16, 32) = 512 blocks
    prodw_kernel<<<grid, BLOCK, 0, stream>>>(x, w, out);
}